// Round 3
// baseline (40862.274 us; speedup 1.0000x reference)
//
#include <hip/hip_runtime.h>
#include <hip/hip_bf16.h>
#include <hip/hip_fp16.h>

// NTM/EMM-GRU scan: B=64, T=512, I=512, H=1024, 3H=3072, P=1024 slots, M=64.
// Round 3 (= Round 2 resubmit; prior bench died on GPU acquisition timeout):
// single persistent kernel, weights resident in LDS across all 512 steps,
// hand-rolled device-scope grid barrier (co-residency forced by LDS:
// 1 block/CU, 192 blocks <= 256 CUs). 2 barriers/step.
//   blocks 0..95  : gh = h@Whh^T (32 output cols each, Whh slice in LDS)
//   blocks 96..127: gi = xin@Wih^T + GRU gates -> h' (3-gate Wih slice in LDS)
//   blocks 128..191: EMM chain for one batch row (memT f16 table in LDS)
// Final out = sigmoid(h_hist@Wout^T) as one big MFMA GEMM (separate kernel).

typedef _Float16 half_t;
typedef _Float16 half8 __attribute__((ext_vector_type(8)));
typedef float f32x4 __attribute__((ext_vector_type(4)));

#define NB 64
#define NT 512
#define NI 512
#define NH 1024
#define G3 3072
#define NP 1024
#define NM 64
#define HB (NB * NH)      // 65536 elems per h snapshot
#define MTP 1032          // padded memT row length (halfs) -> 8-way not 32-way LDS conflict

#define NGH 96
#define NGI 32
#define NEMM 64
#define GRID (NGH + NGI + NEMM)   // 192

__device__ __forceinline__ float sigm(float v) { return 1.f / (1.f + __expf(-v)); }

union SM {
    half_t ghw[32 * 1024];     // 64 KB  : Whh fragment-major slice
    half_t giw[96 * 512];      // 96 KB  : Wih fragment-major slice (3 gates)
    struct {
        half_t memT[NM * MTP]; // 129 KB : padded memT (m-major, f16)
        half_t w16[NP];        // softmax weights (unnormalized)
        float  kqs[NM];
        float  rd[NM];
        float  red[512];
        float  mred[8], sred[8];
    } e;
};

// device-scope grid barrier (all blocks resident: 1 block/CU via LDS)
__device__ __forceinline__ void gbar(unsigned* cnt, unsigned* gen) {
    __syncthreads();
    if (threadIdx.x == 0) {
        __threadfence();
        unsigned g = __hip_atomic_load(gen, __ATOMIC_RELAXED, __HIP_MEMORY_SCOPE_AGENT);
        unsigned a = __hip_atomic_fetch_add(cnt, 1u, __ATOMIC_ACQ_REL, __HIP_MEMORY_SCOPE_AGENT);
        if (a == GRID - 1u) {
            __hip_atomic_store(cnt, 0u, __ATOMIC_RELAXED, __HIP_MEMORY_SCOPE_AGENT);
            __hip_atomic_store(gen, g + 1u, __ATOMIC_RELEASE, __HIP_MEMORY_SCOPE_AGENT);
        } else {
            while (__hip_atomic_load(gen, __ATOMIC_ACQUIRE, __HIP_MEMORY_SCOPE_AGENT) == g) {
                __builtin_amdgcn_s_sleep(2);
            }
        }
        __threadfence();
    }
    __syncthreads();
}

// ---------------- prep: weight conversion + fragment-major images -----------
__global__ __launch_bounds__(256) void prep_kernel(
    const float* __restrict__ Whh, const float* __restrict__ Wih,
    const float* __restrict__ Wout, const float* __restrict__ mem,
    const float* __restrict__ Wk, const float* __restrict__ Wri,
    half_t* __restrict__ Whh_fm, half_t* __restrict__ Wih_fm,
    half_t* __restrict__ Wout16, half_t* __restrict__ memT16p,
    half_t* __restrict__ Wk16, half_t* __restrict__ Wri16,
    half_t* __restrict__ hist0, float* __restrict__ h32,
    unsigned* __restrict__ bar)
{
    size_t stride = (size_t)gridDim.x * blockDim.x;
    size_t t0 = (size_t)blockIdx.x * blockDim.x + threadIdx.x;
    // Whh fragment-major: per gh-block g (32 rows), ct, kk, (kg*16+row)*8+e
    for (size_t i = t0; i < (size_t)3145728; i += stride) {
        unsigned w = (unsigned)i & 32767u;
        int g = (int)(i >> 15);
        int ct = w >> 14, r = w & 16383;
        int kk = r >> 9, u = r & 511;
        int e = u & 7, rr = (u >> 3) & 15, kg = u >> 7;
        int srow = g * 32 + ct * 16 + rr, scol = kk * 32 + kg * 8 + e;
        Whh_fm[i] = (half_t)Whh[(size_t)srow * NH + scol];
    }
    // Wih fragment-major: per gi-block gb: gate gt, ct, kk, frag
    for (size_t i = t0; i < (size_t)1572864; i += stride) {
        int gb = (int)(i / 49152);
        int w = (int)(i % 49152);
        int gt = w / 16384, r = w & 16383;
        int ct = r >> 13, r2 = r & 8191;
        int kk = r2 >> 9, u = r2 & 511;
        int e = u & 7, rr = (u >> 3) & 15, kg = u >> 7;
        int srow = gt * NH + gb * 32 + ct * 16 + rr, scol = kk * 32 + kg * 8 + e;
        Wih_fm[i] = (half_t)Wih[(size_t)srow * NI + scol];
    }
    for (size_t i = t0; i < (size_t)NI * NH; i += stride) Wout16[i] = (half_t)Wout[i];
    for (size_t i = t0; i < (size_t)NP * NM; i += stride) {
        int p = (int)(i >> 6), m = (int)(i & 63);
        memT16p[(size_t)m * MTP + p] = (half_t)mem[i];
    }
    for (size_t i = t0; i < (size_t)NM * NH; i += stride) Wk16[i] = (half_t)Wk[i];
    for (size_t i = t0; i < (size_t)NI * NM; i += stride) Wri16[i] = (half_t)Wri[i];
    for (size_t i = t0; i < (size_t)HB; i += stride) hist0[i] = (half_t)0.f;
    for (size_t i = t0; i < (size_t)2 * HB; i += stride) h32[i] = 0.f;
    if (t0 < 2) bar[t0] = 0u;
}

// ---------------- persistent scan kernel ------------------------------------
__global__ __launch_bounds__(512) void ntm_persist(
    half_t* __restrict__ hist, float* __restrict__ h32,
    const half_t* __restrict__ Whh_fm, const float* __restrict__ bhh,
    float* __restrict__ gh32,
    const half_t* __restrict__ Wih_fm, const float* __restrict__ bih,
    const float* __restrict__ x,
    const half_t* __restrict__ memT16p,
    const half_t* __restrict__ Wk16, const float* __restrict__ bk,
    const half_t* __restrict__ Wri16, const float* __restrict__ bri,
    half_t* __restrict__ xin16,
    unsigned* __restrict__ bar)
{
    __shared__ SM sm;
    const int bid = blockIdx.x, tid = threadIdx.x;
    unsigned* cnt = bar;
    unsigned* gen = bar + 1;

    // ---- one-time LDS staging (linear copies of pre-built images) ----
    if (bid < NGH) {
        const uint4* s = (const uint4*)(Whh_fm + (size_t)bid * 32768);
        uint4* d = (uint4*)sm.ghw;
        for (int i = tid; i < 4096; i += 512) d[i] = s[i];
    } else if (bid < NGH + NGI) {
        const uint4* s = (const uint4*)(Wih_fm + (size_t)(bid - NGH) * 49152);
        uint4* d = (uint4*)sm.giw;
        for (int i = tid; i < 6144; i += 512) d[i] = s[i];
    } else {
        const uint4* s = (const uint4*)memT16p;
        uint4* d = (uint4*)sm.e.memT;
        for (int i = tid; i < 8256; i += 512) d[i] = s[i];
    }
    __syncthreads();

    const int wv = tid >> 6, lane = tid & 63;
    const int mt = wv & 3, ct = wv >> 2;
    const int row = lane & 15, kg = lane >> 4;

    for (int t = 0; t < NT; ++t) {
        float* hprev = h32 + (size_t)(t & 1) * HB;
        float* hnext = h32 + (size_t)((t + 1) & 1) * HB;

        // ================= phase 1: gh + EMM->xin =================
        if (bid < NGH) {
            const half_t* ap = hist + (size_t)t * HB + (size_t)(mt * 16 + row) * NH + kg * 8;
            const half_t* bl = sm.ghw + ct * 16384 + (kg * 16 + row) * 8;
            f32x4 acc = {0.f, 0.f, 0.f, 0.f};
#pragma unroll
            for (int kk = 0; kk < 32; ++kk)
                acc = __builtin_amdgcn_mfma_f32_16x16x32_f16(
                    *(const half8*)(ap + kk * 32), *(const half8*)(bl + kk * 512), acc, 0, 0, 0);
            int n = bid * 32 + ct * 16 + row;
            float bb = bhh[n];
#pragma unroll
            for (int r = 0; r < 4; ++r)
                gh32[(size_t)(mt * 16 + kg * 4 + r) * G3 + n] = acc[r] + bb;
        } else if (bid >= NGH + NGI) {
            const int b = bid - (NGH + NGI);
            float xv = x[((size_t)b * NT + t) * NI + tid];
            const int m = tid & 63, q = tid >> 6;
            {   // S1: kq[m] = h16[b,:].Wk16[m,:] + bk
                const half_t* hp = hist + (size_t)t * HB + (size_t)b * NH + q * 128;
                const half_t* wk = Wk16 + (size_t)m * NH + q * 128;
                float s = 0.f;
#pragma unroll
                for (int j = 0; j < 128; j += 8) {
                    half8 hv = *(const half8*)(hp + j);
                    half8 wvv = *(const half8*)(wk + j);
#pragma unroll
                    for (int e2 = 0; e2 < 8; ++e2) s += (float)hv[e2] * (float)wvv[e2];
                }
                sm.e.red[tid] = s;
            }
            __syncthreads();
            if (tid < 64) {
                float s = bk[tid];
#pragma unroll
                for (int q2 = 0; q2 < 8; ++q2) s += sm.e.red[q2 * 64 + tid];
                sm.e.kqs[tid] = s;
            }
            __syncthreads();
            // S2: scores for p=2tid,2tid+1 + softmax
            float s0 = 0.f, s1 = 0.f;
            {
                const half_t* mp0 = sm.e.memT + tid * 2;
#pragma unroll 8
                for (int m2 = 0; m2 < 64; ++m2) {
                    float km = sm.e.kqs[m2];
                    const half_t* mp = mp0 + m2 * MTP;
                    s0 += km * (float)mp[0];
                    s1 += km * (float)mp[1];
                }
            }
            float lmax = fmaxf(s0, s1);
            for (int o = 32; o; o >>= 1) lmax = fmaxf(lmax, __shfl_xor(lmax, o));
            if ((tid & 63) == 0) sm.e.mred[tid >> 6] = lmax;
            __syncthreads();
            float gmax = sm.e.mred[0];
#pragma unroll
            for (int q2 = 1; q2 < 8; ++q2) gmax = fmaxf(gmax, sm.e.mred[q2]);
            float e0 = __expf(s0 - gmax), e1 = __expf(s1 - gmax);
            float ls = e0 + e1;
            for (int o = 32; o; o >>= 1) ls += __shfl_xor(ls, o);
            if ((tid & 63) == 0) sm.e.sred[tid >> 6] = ls;
            sm.e.w16[tid * 2] = (half_t)e0;
            sm.e.w16[tid * 2 + 1] = (half_t)e1;
            __syncthreads();
            float wsum = 0.f;
#pragma unroll
            for (int q2 = 0; q2 < 8; ++q2) wsum += sm.e.sred[q2];
            float winv = 1.f / wsum;
            {   // S4: read[m] = (w . memT[m,:]) * winv
                const half_t* mp = sm.e.memT + m * MTP + q * 128;
                const half_t* wp = sm.e.w16 + q * 128;
                float s = 0.f;
#pragma unroll
                for (int p0 = 0; p0 < 128; p0 += 8) {
                    half8 mv = *(const half8*)(mp + p0);
                    half8 wv2 = *(const half8*)(wp + p0);
#pragma unroll
                    for (int e2 = 0; e2 < 8; ++e2) s += (float)mv[e2] * (float)wv2[e2];
                }
                sm.e.red[tid] = s;
            }
            __syncthreads();
            if (tid < 64) {
                float s = 0.f;
#pragma unroll
                for (int q2 = 0; q2 < 8; ++q2) s += sm.e.red[q2 * 64 + tid];
                sm.e.rd[tid] = s * winv;
            }
            __syncthreads();
            {   // S5: xin = x + relu(read @ Wri^T + bri)
                const half_t* wr = Wri16 + (size_t)tid * NM;
                float s = bri[tid];
#pragma unroll
                for (int m2 = 0; m2 < 64; m2 += 8) {
                    half8 wv2 = *(const half8*)(wr + m2);
#pragma unroll
                    for (int e2 = 0; e2 < 8; ++e2) s += sm.e.rd[m2 + e2] * (float)wv2[e2];
                }
                s = fmaxf(s, 0.f) + xv;
                xin16[(size_t)b * NI + tid] = (half_t)s;
            }
        }
        gbar(cnt, gen);

        // ================= phase 2: gi + gates -> h(t+1) =================
        if (bid >= NGH && bid < NGH + NGI) {
            const int gb = bid - NGH;
            const half_t* ap = xin16 + (size_t)(mt * 16 + row) * NI + kg * 8;
            const half_t* bR = sm.giw + ct * 8192 + (kg * 16 + row) * 8;
            const half_t* bZ = bR + 16384;
            const half_t* bN = bR + 32768;
            f32x4 aR = {0.f,0.f,0.f,0.f}, aZ = {0.f,0.f,0.f,0.f}, aN = {0.f,0.f,0.f,0.f};
#pragma unroll
            for (int kk = 0; kk < 16; ++kk) {
                half8 a = *(const half8*)(ap + kk * 32);
                aR = __builtin_amdgcn_mfma_f32_16x16x32_f16(a, *(const half8*)(bR + kk * 512), aR, 0, 0, 0);
                aZ = __builtin_amdgcn_mfma_f32_16x16x32_f16(a, *(const half8*)(bZ + kk * 512), aZ, 0, 0, 0);
                aN = __builtin_amdgcn_mfma_f32_16x16x32_f16(a, *(const half8*)(bN + kk * 512), aN, 0, 0, 0);
            }
            int n = gb * 32 + ct * 16 + row;
            float biR = bih[n], biZ = bih[NH + n], biN = bih[2 * NH + n];
#pragma unroll
            for (int r = 0; r < 4; ++r) {
                int b2 = mt * 16 + kg * 4 + r;
                float ghr = gh32[(size_t)b2 * G3 + n];
                float ghz = gh32[(size_t)b2 * G3 + NH + n];
                float ghn = gh32[(size_t)b2 * G3 + 2 * NH + n];
                float rg = sigm(aR[r] + biR + ghr);
                float zg = sigm(aZ[r] + biZ + ghz);
                float ng = tanhf(aN[r] + biN + rg * ghn);
                float hp = hprev[(size_t)b2 * NH + n];
                float hn = (1.f - zg) * ng + zg * hp;
                hnext[(size_t)b2 * NH + n] = hn;
                hist[(size_t)(t + 1) * HB + (size_t)b2 * NH + n] = (half_t)hn;
            }
        }
        gbar(cnt, gen);
    }
}

// ---------------- final: out[b,t,:] = sigmoid(h_{t+1} @ Wout^T + bout) ------
__global__ __launch_bounds__(256) void out_kernel(
    const half_t* __restrict__ hist,
    const half_t* __restrict__ Wout16,
    const float* __restrict__ bout,
    float* __restrict__ out)
{
    int tid = threadIdx.x;
    int widx = tid >> 6, lane = tid & 63;
    int m0 = blockIdx.x * 64 + widx * 16;
    int row = lane & 15, kg = lane >> 4;
    const half_t* ap = hist + HB + (size_t)(m0 + row) * NH + kg * 8;
    for (int ctl = 0; ctl < 32; ++ctl) {
        int n0 = ctl * 16;
        const half_t* bp = Wout16 + (size_t)(n0 + row) * NH + kg * 8;
        f32x4 acc = {0.f, 0.f, 0.f, 0.f};
#pragma unroll
        for (int kk = 0; kk < 32; ++kk) {
            acc = __builtin_amdgcn_mfma_f32_16x16x32_f16(
                *(const half8*)(ap + kk * 32), *(const half8*)(bp + kk * 32), acc, 0, 0, 0);
        }
        int n = n0 + row;
        float bo = bout[n];
#pragma unroll
        for (int r = 0; r < 4; ++r) {
            int m = m0 + kg * 4 + r;
            int b2 = m & 63, tt = m >> 6;
            out[((size_t)b2 * NT + tt) * NI + n] = sigm(acc[r] + bo);
        }
    }
}

extern "C" void kernel_launch(void* const* d_in, const int* in_sizes, int n_in,
                              void* d_out, int out_size, void* d_ws, size_t ws_size,
                              hipStream_t stream) {
    const float* x    = (const float*)d_in[0];
    const float* mem  = (const float*)d_in[1];
    const float* Wk   = (const float*)d_in[2];
    const float* bk   = (const float*)d_in[3];
    const float* Wri  = (const float*)d_in[4];
    const float* bri  = (const float*)d_in[5];
    const float* Wih  = (const float*)d_in[6];
    const float* Whh  = (const float*)d_in[7];
    const float* bih  = (const float*)d_in[8];
    const float* bhh  = (const float*)d_in[9];
    const float* Wout = (const float*)d_in[10];
    const float* bout = (const float*)d_in[11];
    float* out = (float*)d_out;

    size_t off = 0;
    char* wsb = (char*)d_ws;
    auto carve = [&](size_t bytes) -> char* {
        char* p = wsb + off;
        off += (bytes + 255) & ~(size_t)255;
        return p;
    };
    half_t* Whh_fm  = (half_t*)carve((size_t)G3 * NH * 2);
    half_t* Wih_fm  = (half_t*)carve((size_t)G3 * NI * 2);
    half_t* Wout16  = (half_t*)carve((size_t)NI * NH * 2);
    half_t* memT16p = (half_t*)carve((size_t)NM * MTP * 2);
    half_t* Wk16    = (half_t*)carve((size_t)NM * NH * 2);
    half_t* Wri16   = (half_t*)carve((size_t)NI * NM * 2);
    half_t* hist    = (half_t*)carve((size_t)(NT + 1) * HB * 2);
    float*  h32     = (float*)carve((size_t)2 * HB * 4);
    float*  gh32    = (float*)carve((size_t)NB * G3 * 4);
    half_t* xin16   = (half_t*)carve((size_t)NB * NI * 2);
    unsigned* bar   = (unsigned*)carve(256);
    (void)ws_size; (void)in_sizes; (void)n_in; (void)out_size;

    prep_kernel<<<dim3(2048), dim3(256), 0, stream>>>(
        Whh, Wih, Wout, mem, Wk, Wri,
        Whh_fm, Wih_fm, Wout16, memT16p, Wk16, Wri16, hist, h32, bar);

    ntm_persist<<<dim3(GRID), dim3(512), 0, stream>>>(
        hist, h32, Whh_fm, bhh, gh32, Wih_fm, bih, x,
        memT16p, Wk16, bk, Wri16, bri, xin16, bar);

    out_kernel<<<dim3(512), dim3(256), 0, stream>>>(hist, Wout16, bout, out);
}

// Round 7
// 13477.650 us; speedup vs baseline: 3.0319x; 3.0319x over previous
//
#include <hip/hip_runtime.h>
#include <hip/hip_bf16.h>
#include <hip/hip_fp16.h>

// NTM/EMM-GRU scan: B=64, T=512, I=512, H=1024, 3H=3072, P=1024 slots, M=64.
// Round 7 (= Round 4/5/6 resubmit; prior benches died on infra failures):
// persistent kernel, weights LDS-resident across all 512 steps; grid barrier
// rebuilt vs R3: RELAXED polls, exactly one release fence (wbl2) on arrival
// and one acquire fence (inv) on exit per block -- the coherence minimum.
// R3's ACQUIRE-poll barrier caused an L2 invalidate/writeback storm
// (VALUBusy 0.98%, 1 GB HBM churn, ~40 us/barrier).
//   blocks 0..95  : gh = h@Whh^T (32 output cols each, Whh slice in LDS)
//   blocks 96..127: gi = xin@Wih^T + GRU gates -> h' (3-gate Wih slice in LDS)
//   blocks 128..191: EMM chain for one batch row (memT f16 table in LDS)
// Final out = sigmoid(h_hist@Wout^T) as one big MFMA GEMM (separate kernel).

typedef _Float16 half_t;
typedef _Float16 half8 __attribute__((ext_vector_type(8)));
typedef float f32x4 __attribute__((ext_vector_type(4)));

#define NB 64
#define NT 512
#define NI 512
#define NH 1024
#define G3 3072
#define NP 1024
#define NM 64
#define HB (NB * NH)      // 65536 elems per h snapshot
#define MTP 1032          // padded memT row length (halfs) -> 8-way not 32-way LDS conflict

#define NGH 96
#define NGI 32
#define NEMM 64
#define GRID (NGH + NGI + NEMM)   // 192

__device__ __forceinline__ float sigm(float v) { return 1.f / (1.f + __expf(-v)); }

union SM {
    half_t ghw[32 * 1024];     // 64 KB  : Whh fragment-major slice
    half_t giw[96 * 512];      // 96 KB  : Wih fragment-major slice (3 gates)
    struct {
        half_t memT[NM * MTP]; // 129 KB : padded memT (m-major, f16)
        half_t w16[NP];        // softmax weights (unnormalized)
        float  kqs[NM];
        float  rd[NM];
        float  red[512];
        float  mred[8], sred[8];
    } e;
};

// device-scope grid barrier, cache-maintenance-minimal.
// cnt at bar[0], gen at bar[32] (separate 128B lines).
__device__ __forceinline__ void gbar(unsigned* bar) {
    __syncthreads();
    if (threadIdx.x == 0) {
        unsigned* cnt = bar;
        unsigned* gen = bar + 32;
        // release: flush this XCD's dirty L2 (phase writes) to coherence point
        __builtin_amdgcn_fence(__ATOMIC_RELEASE, "agent");
        unsigned g = __hip_atomic_load(gen, __ATOMIC_RELAXED, __HIP_MEMORY_SCOPE_AGENT);
        unsigned a = __hip_atomic_fetch_add(cnt, 1u, __ATOMIC_RELAXED, __HIP_MEMORY_SCOPE_AGENT);
        if (a == GRID - 1u) {
            __hip_atomic_store(cnt, 0u, __ATOMIC_RELAXED, __HIP_MEMORY_SCOPE_AGENT);
            // release store: orders the cnt reset before the gen flip
            __hip_atomic_store(gen, g + 1u, __ATOMIC_RELEASE, __HIP_MEMORY_SCOPE_AGENT);
        } else {
            // RELAXED polls: no cache ops per iteration
            while (__hip_atomic_load(gen, __ATOMIC_RELAXED, __HIP_MEMORY_SCOPE_AGENT) == g) {
                __builtin_amdgcn_s_sleep(4);
            }
        }
        // acquire: invalidate stale L1/L2 so peers' phase writes are visible
        __builtin_amdgcn_fence(__ATOMIC_ACQUIRE, "agent");
    }
    __syncthreads();
}

// ---------------- prep: weight conversion + fragment-major images -----------
__global__ __launch_bounds__(256) void prep_kernel(
    const float* __restrict__ Whh, const float* __restrict__ Wih,
    const float* __restrict__ Wout, const float* __restrict__ mem,
    const float* __restrict__ Wk, const float* __restrict__ Wri,
    half_t* __restrict__ Whh_fm, half_t* __restrict__ Wih_fm,
    half_t* __restrict__ Wout16, half_t* __restrict__ memT16p,
    half_t* __restrict__ Wk16, half_t* __restrict__ Wri16,
    half_t* __restrict__ hist0, float* __restrict__ h32,
    unsigned* __restrict__ bar)
{
    size_t stride = (size_t)gridDim.x * blockDim.x;
    size_t t0 = (size_t)blockIdx.x * blockDim.x + threadIdx.x;
    // Whh fragment-major: per gh-block g (32 rows), ct, kk, (kg*16+row)*8+e
    for (size_t i = t0; i < (size_t)3145728; i += stride) {
        unsigned w = (unsigned)i & 32767u;
        int g = (int)(i >> 15);
        int ct = w >> 14, r = w & 16383;
        int kk = r >> 9, u = r & 511;
        int e = u & 7, rr = (u >> 3) & 15, kg = u >> 7;
        int srow = g * 32 + ct * 16 + rr, scol = kk * 32 + kg * 8 + e;
        Whh_fm[i] = (half_t)Whh[(size_t)srow * NH + scol];
    }
    // Wih fragment-major: per gi-block gb: gate gt, ct, kk, frag
    for (size_t i = t0; i < (size_t)1572864; i += stride) {
        int gb = (int)(i / 49152);
        int w = (int)(i % 49152);
        int gt = w / 16384, r = w & 16383;
        int ct = r >> 13, r2 = r & 8191;
        int kk = r2 >> 9, u = r2 & 511;
        int e = u & 7, rr = (u >> 3) & 15, kg = u >> 7;
        int srow = gt * NH + gb * 32 + ct * 16 + rr, scol = kk * 32 + kg * 8 + e;
        Wih_fm[i] = (half_t)Wih[(size_t)srow * NI + scol];
    }
    for (size_t i = t0; i < (size_t)NI * NH; i += stride) Wout16[i] = (half_t)Wout[i];
    for (size_t i = t0; i < (size_t)NP * NM; i += stride) {
        int p = (int)(i >> 6), m = (int)(i & 63);
        memT16p[(size_t)m * MTP + p] = (half_t)mem[i];
    }
    for (size_t i = t0; i < (size_t)NM * NH; i += stride) Wk16[i] = (half_t)Wk[i];
    for (size_t i = t0; i < (size_t)NI * NM; i += stride) Wri16[i] = (half_t)Wri[i];
    for (size_t i = t0; i < (size_t)HB; i += stride) hist0[i] = (half_t)0.f;
    for (size_t i = t0; i < (size_t)2 * HB; i += stride) h32[i] = 0.f;
    if (t0 < 64) bar[t0] = 0u;
}

// ---------------- persistent scan kernel ------------------------------------
__global__ __launch_bounds__(512) void ntm_persist(
    half_t* __restrict__ hist, float* __restrict__ h32,
    const half_t* __restrict__ Whh_fm, const float* __restrict__ bhh,
    float* __restrict__ gh32,
    const half_t* __restrict__ Wih_fm, const float* __restrict__ bih,
    const float* __restrict__ x,
    const half_t* __restrict__ memT16p,
    const half_t* __restrict__ Wk16, const float* __restrict__ bk,
    const half_t* __restrict__ Wri16, const float* __restrict__ bri,
    half_t* __restrict__ xin16,
    unsigned* __restrict__ bar)
{
    __shared__ SM sm;
    const int bid = blockIdx.x, tid = threadIdx.x;

    // ---- one-time LDS staging (linear copies of pre-built images) ----
    if (bid < NGH) {
        const uint4* s = (const uint4*)(Whh_fm + (size_t)bid * 32768);
        uint4* d = (uint4*)sm.ghw;
        for (int i = tid; i < 4096; i += 512) d[i] = s[i];
    } else if (bid < NGH + NGI) {
        const uint4* s = (const uint4*)(Wih_fm + (size_t)(bid - NGH) * 49152);
        uint4* d = (uint4*)sm.giw;
        for (int i = tid; i < 6144; i += 512) d[i] = s[i];
    } else {
        const uint4* s = (const uint4*)memT16p;
        uint4* d = (uint4*)sm.e.memT;
        for (int i = tid; i < 8256; i += 512) d[i] = s[i];
    }
    __syncthreads();

    const int wv = tid >> 6, lane = tid & 63;
    const int mt = wv & 3, ct = wv >> 2;
    const int row = lane & 15, kg = lane >> 4;

    for (int t = 0; t < NT; ++t) {
        float* hprev = h32 + (size_t)(t & 1) * HB;
        float* hnext = h32 + (size_t)((t + 1) & 1) * HB;

        // ================= phase 1: gh + EMM->xin =================
        if (bid < NGH) {
            const half_t* ap = hist + (size_t)t * HB + (size_t)(mt * 16 + row) * NH + kg * 8;
            const half_t* bl = sm.ghw + ct * 16384 + (kg * 16 + row) * 8;
            f32x4 acc = {0.f, 0.f, 0.f, 0.f};
#pragma unroll
            for (int kk = 0; kk < 32; ++kk)
                acc = __builtin_amdgcn_mfma_f32_16x16x32_f16(
                    *(const half8*)(ap + kk * 32), *(const half8*)(bl + kk * 512), acc, 0, 0, 0);
            int n = bid * 32 + ct * 16 + row;
            float bb = bhh[n];
#pragma unroll
            for (int r = 0; r < 4; ++r)
                gh32[(size_t)(mt * 16 + kg * 4 + r) * G3 + n] = acc[r] + bb;
        } else if (bid >= NGH + NGI) {
            const int b = bid - (NGH + NGI);
            float xv = x[((size_t)b * NT + t) * NI + tid];
            const int m = tid & 63, q = tid >> 6;
            {   // S1: kq[m] = h16[b,:].Wk16[m,:] + bk
                const half_t* hp = hist + (size_t)t * HB + (size_t)b * NH + q * 128;
                const half_t* wk = Wk16 + (size_t)m * NH + q * 128;
                float s = 0.f;
#pragma unroll
                for (int j = 0; j < 128; j += 8) {
                    half8 hv = *(const half8*)(hp + j);
                    half8 wvv = *(const half8*)(wk + j);
#pragma unroll
                    for (int e2 = 0; e2 < 8; ++e2) s += (float)hv[e2] * (float)wvv[e2];
                }
                sm.e.red[tid] = s;
            }
            __syncthreads();
            if (tid < 64) {
                float s = bk[tid];
#pragma unroll
                for (int q2 = 0; q2 < 8; ++q2) s += sm.e.red[q2 * 64 + tid];
                sm.e.kqs[tid] = s;
            }
            __syncthreads();
            // S2: scores for p=2tid,2tid+1 + softmax
            float s0 = 0.f, s1 = 0.f;
            {
                const half_t* mp0 = sm.e.memT + tid * 2;
#pragma unroll 8
                for (int m2 = 0; m2 < 64; ++m2) {
                    float km = sm.e.kqs[m2];
                    const half_t* mp = mp0 + m2 * MTP;
                    s0 += km * (float)mp[0];
                    s1 += km * (float)mp[1];
                }
            }
            float lmax = fmaxf(s0, s1);
            for (int o = 32; o; o >>= 1) lmax = fmaxf(lmax, __shfl_xor(lmax, o));
            if ((tid & 63) == 0) sm.e.mred[tid >> 6] = lmax;
            __syncthreads();
            float gmax = sm.e.mred[0];
#pragma unroll
            for (int q2 = 1; q2 < 8; ++q2) gmax = fmaxf(gmax, sm.e.mred[q2]);
            float e0 = __expf(s0 - gmax), e1 = __expf(s1 - gmax);
            float ls = e0 + e1;
            for (int o = 32; o; o >>= 1) ls += __shfl_xor(ls, o);
            if ((tid & 63) == 0) sm.e.sred[tid >> 6] = ls;
            sm.e.w16[tid * 2] = (half_t)e0;
            sm.e.w16[tid * 2 + 1] = (half_t)e1;
            __syncthreads();
            float wsum = 0.f;
#pragma unroll
            for (int q2 = 0; q2 < 8; ++q2) wsum += sm.e.sred[q2];
            float winv = 1.f / wsum;
            {   // S4: read[m] = (w . memT[m,:]) * winv
                const half_t* mp = sm.e.memT + m * MTP + q * 128;
                const half_t* wp = sm.e.w16 + q * 128;
                float s = 0.f;
#pragma unroll
                for (int p0 = 0; p0 < 128; p0 += 8) {
                    half8 mv = *(const half8*)(mp + p0);
                    half8 wv2 = *(const half8*)(wp + p0);
#pragma unroll
                    for (int e2 = 0; e2 < 8; ++e2) s += (float)mv[e2] * (float)wv2[e2];
                }
                sm.e.red[tid] = s;
            }
            __syncthreads();
            if (tid < 64) {
                float s = 0.f;
#pragma unroll
                for (int q2 = 0; q2 < 8; ++q2) s += sm.e.red[q2 * 64 + tid];
                sm.e.rd[tid] = s * winv;
            }
            __syncthreads();
            {   // S5: xin = x + relu(read @ Wri^T + bri)
                const half_t* wr = Wri16 + (size_t)tid * NM;
                float s = bri[tid];
#pragma unroll
                for (int m2 = 0; m2 < 64; m2 += 8) {
                    half8 wv2 = *(const half8*)(wr + m2);
#pragma unroll
                    for (int e2 = 0; e2 < 8; ++e2) s += sm.e.rd[m2 + e2] * (float)wv2[e2];
                }
                s = fmaxf(s, 0.f) + xv;
                xin16[(size_t)b * NI + tid] = (half_t)s;
            }
        }
        gbar(bar);

        // ================= phase 2: gi + gates -> h(t+1) =================
        if (bid >= NGH && bid < NGH + NGI) {
            const int gb = bid - NGH;
            const half_t* ap = xin16 + (size_t)(mt * 16 + row) * NI + kg * 8;
            const half_t* bR = sm.giw + ct * 8192 + (kg * 16 + row) * 8;
            const half_t* bZ = bR + 16384;
            const half_t* bN = bR + 32768;
            f32x4 aR = {0.f,0.f,0.f,0.f}, aZ = {0.f,0.f,0.f,0.f}, aN = {0.f,0.f,0.f,0.f};
#pragma unroll
            for (int kk = 0; kk < 16; ++kk) {
                half8 a = *(const half8*)(ap + kk * 32);
                aR = __builtin_amdgcn_mfma_f32_16x16x32_f16(a, *(const half8*)(bR + kk * 512), aR, 0, 0, 0);
                aZ = __builtin_amdgcn_mfma_f32_16x16x32_f16(a, *(const half8*)(bZ + kk * 512), aZ, 0, 0, 0);
                aN = __builtin_amdgcn_mfma_f32_16x16x32_f16(a, *(const half8*)(bN + kk * 512), aN, 0, 0, 0);
            }
            int n = gb * 32 + ct * 16 + row;
            float biR = bih[n], biZ = bih[NH + n], biN = bih[2 * NH + n];
#pragma unroll
            for (int r = 0; r < 4; ++r) {
                int b2 = mt * 16 + kg * 4 + r;
                float ghr = gh32[(size_t)b2 * G3 + n];
                float ghz = gh32[(size_t)b2 * G3 + NH + n];
                float ghn = gh32[(size_t)b2 * G3 + 2 * NH + n];
                float rg = sigm(aR[r] + biR + ghr);
                float zg = sigm(aZ[r] + biZ + ghz);
                float ng = tanhf(aN[r] + biN + rg * ghn);
                float hp = hprev[(size_t)b2 * NH + n];
                float hn = (1.f - zg) * ng + zg * hp;
                hnext[(size_t)b2 * NH + n] = hn;
                hist[(size_t)(t + 1) * HB + (size_t)b2 * NH + n] = (half_t)hn;
            }
        }
        gbar(bar);
    }
}

// ---------------- final: out[b,t,:] = sigmoid(h_{t+1} @ Wout^T + bout) ------
__global__ __launch_bounds__(256) void out_kernel(
    const half_t* __restrict__ hist,
    const half_t* __restrict__ Wout16,
    const float* __restrict__ bout,
    float* __restrict__ out)
{
    int tid = threadIdx.x;
    int widx = tid >> 6, lane = tid & 63;
    int m0 = blockIdx.x * 64 + widx * 16;
    int row = lane & 15, kg = lane >> 4;
    const half_t* ap = hist + HB + (size_t)(m0 + row) * NH + kg * 8;
    for (int ctl = 0; ctl < 32; ++ctl) {
        int n0 = ctl * 16;
        const half_t* bp = Wout16 + (size_t)(n0 + row) * NH + kg * 8;
        f32x4 acc = {0.f, 0.f, 0.f, 0.f};
#pragma unroll
        for (int kk = 0; kk < 32; ++kk) {
            acc = __builtin_amdgcn_mfma_f32_16x16x32_f16(
                *(const half8*)(ap + kk * 32), *(const half8*)(bp + kk * 32), acc, 0, 0, 0);
        }
        int n = n0 + row;
        float bo = bout[n];
#pragma unroll
        for (int r = 0; r < 4; ++r) {
            int m = m0 + kg * 4 + r;
            int b2 = m & 63, tt = m >> 6;
            out[((size_t)b2 * NT + tt) * NI + n] = sigm(acc[r] + bo);
        }
    }
}

extern "C" void kernel_launch(void* const* d_in, const int* in_sizes, int n_in,
                              void* d_out, int out_size, void* d_ws, size_t ws_size,
                              hipStream_t stream) {
    const float* x    = (const float*)d_in[0];
    const float* mem  = (const float*)d_in[1];
    const float* Wk   = (const float*)d_in[2];
    const float* bk   = (const float*)d_in[3];
    const float* Wri  = (const float*)d_in[4];
    const float* bri  = (const float*)d_in[5];
    const float* Wih  = (const float*)d_in[6];
    const float* Whh  = (const float*)d_in[7];
    const float* bih  = (const float*)d_in[8];
    const float* bhh  = (const float*)d_in[9];
    const float* Wout = (const float*)d_in[10];
    const float* bout = (const float*)d_in[11];
    float* out = (float*)d_out;

    size_t off = 0;
    char* wsb = (char*)d_ws;
    auto carve = [&](size_t bytes) -> char* {
        char* p = wsb + off;
        off += (bytes + 255) & ~(size_t)255;
        return p;
    };
    half_t* Whh_fm  = (half_t*)carve((size_t)G3 * NH * 2);
    half_t* Wih_fm  = (half_t*)carve((size_t)G3 * NI * 2);
    half_t* Wout16  = (half_t*)carve((size_t)NI * NH * 2);
    half_t* memT16p = (half_t*)carve((size_t)NM * MTP * 2);
    half_t* Wk16    = (half_t*)carve((size_t)NM * NH * 2);
    half_t* Wri16   = (half_t*)carve((size_t)NI * NM * 2);
    half_t* hist    = (half_t*)carve((size_t)(NT + 1) * HB * 2);
    float*  h32     = (float*)carve((size_t)2 * HB * 4);
    float*  gh32    = (float*)carve((size_t)NB * G3 * 4);
    half_t* xin16   = (half_t*)carve((size_t)NB * NI * 2);
    unsigned* bar   = (unsigned*)carve(256);
    (void)ws_size; (void)in_sizes; (void)n_in; (void)out_size;

    prep_kernel<<<dim3(2048), dim3(256), 0, stream>>>(
        Whh, Wih, Wout, mem, Wk, Wri,
        Whh_fm, Wih_fm, Wout16, memT16p, Wk16, Wri16, hist, h32, bar);

    ntm_persist<<<dim3(GRID), dim3(512), 0, stream>>>(
        hist, h32, Whh_fm, bhh, gh32, Wih_fm, bih, x,
        memT16p, Wk16, bk, Wri16, bri, xin16, bar);

    out_kernel<<<dim3(512), dim3(256), 0, stream>>>(hist, Wout16, bout, out);
}

// Round 8
// 11029.194 us; speedup vs baseline: 3.7049x; 1.2220x over previous
//
#include <hip/hip_runtime.h>
#include <hip/hip_bf16.h>
#include <hip/hip_fp16.h>

// NTM/EMM-GRU scan: B=64, T=512, I=512, H=1024, 3H=3072, P=1024 slots, M=64.
// Round 8: fence-FREE persistent kernel. R7 showed 12.5 us/barrier from the
// per-barrier wbl2+inv (full L2 tag-walks) and 417 MB of table refetch from
// the inv. Now: zero fences. Cross-block data moves with device-scope
// (agent, relaxed) atomic loads/stores that bypass stale caches per-access;
// hist/xin are per-step rings so readers' plain cached loads cold-miss to L3
// (fresh address -> no stale line possible); h32 is block-private. Barrier is
// monotonic relaxed-atomic count + relaxed polls (no reset, no fences).
//   blocks 0..95  : gh = h@Whh^T (32 output cols each, Whh slice in LDS)
//   blocks 96..127: gi = xin@Wih^T + GRU gates -> h' (3-gate Wih slice in LDS)
//   blocks 128..191: EMM chain for one batch row (memT f16 table in LDS)
// Final out = sigmoid(h_hist@Wout^T) as one big MFMA GEMM (separate kernel).

typedef _Float16 half_t;
typedef _Float16 half8 __attribute__((ext_vector_type(8)));
typedef float f32x4 __attribute__((ext_vector_type(4)));

#define NB 64
#define NT 512
#define NI 512
#define NH 1024
#define G3 3072
#define NP 1024
#define NM 64
#define HB (NB * NH)      // 65536 elems per h snapshot
#define MTP 1032          // padded memT row length (halfs)

#define NGH 96
#define NGI 32
#define NEMM 64
#define GRID (NGH + NGI + NEMM)   // 192

__device__ __forceinline__ float sigm(float v) { return 1.f / (1.f + __expf(-v)); }

union SM {
    half_t ghw[32 * 1024];     // 64 KB  : Whh fragment-major slice
    half_t giw[96 * 512];      // 96 KB  : Wih fragment-major slice (3 gates)
    struct {
        half_t memT[NM * MTP]; // 129 KB : padded memT (m-major, f16)
        half_t w16[NP];
        float  kqs[NM];
        float  rd[NM];
        float  red[512];
        float  mred[8], sred[8];
    } e;
};

// fence-free grid barrier: monotonic arrival count, relaxed agent atomics.
// __syncthreads() drains vmcnt before s_barrier (HIP semantics), so all of
// this block's device-scope stores are complete before tid0 signals.
__device__ __forceinline__ void gbar(unsigned* bar, unsigned bidx) {
    __syncthreads();
    if (threadIdx.x == 0) {
        unsigned* cnt = bar;
        unsigned* gen = bar + 32;   // separate 128B line
        unsigned a = __hip_atomic_fetch_add(cnt, 1u, __ATOMIC_RELAXED, __HIP_MEMORY_SCOPE_AGENT);
        if (a == bidx * GRID - 1u) {
            __hip_atomic_store(gen, bidx, __ATOMIC_RELAXED, __HIP_MEMORY_SCOPE_AGENT);
        } else {
            while (__hip_atomic_load(gen, __ATOMIC_RELAXED, __HIP_MEMORY_SCOPE_AGENT) < bidx) {
                __builtin_amdgcn_s_sleep(4);
            }
        }
    }
    __syncthreads();
}

// ---------------- prep: weight conversion + fragment-major images -----------
__global__ __launch_bounds__(256) void prep_kernel(
    const float* __restrict__ Whh, const float* __restrict__ Wih,
    const float* __restrict__ Wout, const float* __restrict__ mem,
    const float* __restrict__ Wk, const float* __restrict__ Wri,
    half_t* __restrict__ Whh_fm, half_t* __restrict__ Wih_fm,
    half_t* __restrict__ Wout16, half_t* __restrict__ memT16p,
    half_t* __restrict__ Wk16, half_t* __restrict__ Wri16,
    half_t* __restrict__ hist0, float* __restrict__ h32,
    unsigned* __restrict__ bar)
{
    size_t stride = (size_t)gridDim.x * blockDim.x;
    size_t t0 = (size_t)blockIdx.x * blockDim.x + threadIdx.x;
    for (size_t i = t0; i < (size_t)3145728; i += stride) {
        unsigned w = (unsigned)i & 32767u;
        int g = (int)(i >> 15);
        int ct = w >> 14, r = w & 16383;
        int kk = r >> 9, u = r & 511;
        int e = u & 7, rr = (u >> 3) & 15, kg = u >> 7;
        int srow = g * 32 + ct * 16 + rr, scol = kk * 32 + kg * 8 + e;
        Whh_fm[i] = (half_t)Whh[(size_t)srow * NH + scol];
    }
    for (size_t i = t0; i < (size_t)1572864; i += stride) {
        int gb = (int)(i / 49152);
        int w = (int)(i % 49152);
        int gt = w / 16384, r = w & 16383;
        int ct = r >> 13, r2 = r & 8191;
        int kk = r2 >> 9, u = r2 & 511;
        int e = u & 7, rr = (u >> 3) & 15, kg = u >> 7;
        int srow = gt * NH + gb * 32 + ct * 16 + rr, scol = kk * 32 + kg * 8 + e;
        Wih_fm[i] = (half_t)Wih[(size_t)srow * NI + scol];
    }
    for (size_t i = t0; i < (size_t)NI * NH; i += stride) Wout16[i] = (half_t)Wout[i];
    for (size_t i = t0; i < (size_t)NP * NM; i += stride) {
        int p = (int)(i >> 6), m = (int)(i & 63);
        memT16p[(size_t)m * MTP + p] = (half_t)mem[i];
    }
    for (size_t i = t0; i < (size_t)NM * NH; i += stride) Wk16[i] = (half_t)Wk[i];
    for (size_t i = t0; i < (size_t)NI * NM; i += stride) Wri16[i] = (half_t)Wri[i];
    for (size_t i = t0; i < (size_t)HB; i += stride) hist0[i] = (half_t)0.f;
    for (size_t i = t0; i < (size_t)2 * HB; i += stride) h32[i] = 0.f;
    if (t0 < 64) bar[t0] = 0u;
}

// ---------------- persistent scan kernel ------------------------------------
__global__ __launch_bounds__(512) void ntm_persist(
    half_t* __restrict__ hist, float* __restrict__ h32,
    const half_t* __restrict__ Whh_fm, const float* __restrict__ bhh,
    float* __restrict__ gh32,
    const half_t* __restrict__ Wih_fm, const float* __restrict__ bih,
    const float* __restrict__ x,
    const half_t* __restrict__ memT16p,
    const half_t* __restrict__ Wk16, const float* __restrict__ bk,
    const half_t* __restrict__ Wri16, const float* __restrict__ bri,
    half_t* __restrict__ xinR,
    unsigned* __restrict__ bar)
{
    __shared__ SM sm;
    const int bid = blockIdx.x, tid = threadIdx.x;

    if (bid < NGH) {
        const uint4* s = (const uint4*)(Whh_fm + (size_t)bid * 32768);
        uint4* d = (uint4*)sm.ghw;
        for (int i = tid; i < 4096; i += 512) d[i] = s[i];
    } else if (bid < NGH + NGI) {
        const uint4* s = (const uint4*)(Wih_fm + (size_t)(bid - NGH) * 49152);
        uint4* d = (uint4*)sm.giw;
        for (int i = tid; i < 6144; i += 512) d[i] = s[i];
    } else {
        const uint4* s = (const uint4*)memT16p;
        uint4* d = (uint4*)sm.e.memT;
        for (int i = tid; i < 8256; i += 512) d[i] = s[i];
    }
    __syncthreads();

    const int wv = tid >> 6, lane = tid & 63;
    const int mt = wv & 3, ct = wv >> 2;
    const int row = lane & 15, kg = lane >> 4;
    unsigned bidx = 0;

    for (int t = 0; t < NT; ++t) {
        float* hprev = h32 + (size_t)(t & 1) * HB;
        float* hnext = h32 + (size_t)((t + 1) & 1) * HB;
        half_t* xin = xinR + (size_t)t * (NB * NI);   // per-step ring: fresh addrs

        // ================= phase 1: gh + EMM->xin =================
        if (bid < NGH) {
            const half_t* ap = hist + (size_t)t * HB + (size_t)(mt * 16 + row) * NH + kg * 8;
            const half_t* bl = sm.ghw + ct * 16384 + (kg * 16 + row) * 8;
            f32x4 acc = {0.f, 0.f, 0.f, 0.f};
#pragma unroll
            for (int kk = 0; kk < 32; ++kk)
                acc = __builtin_amdgcn_mfma_f32_16x16x32_f16(
                    *(const half8*)(ap + kk * 32), *(const half8*)(bl + kk * 512), acc, 0, 0, 0);
            int n = bid * 32 + ct * 16 + row;
            float bb = bhh[n];
#pragma unroll
            for (int r = 0; r < 4; ++r)
                __hip_atomic_store(&gh32[(size_t)(mt * 16 + kg * 4 + r) * G3 + n],
                                   acc[r] + bb, __ATOMIC_RELAXED, __HIP_MEMORY_SCOPE_AGENT);
        } else if (bid >= NGH + NGI) {
            const int b = bid - (NGH + NGI);
            float xv = x[((size_t)b * NT + t) * NI + tid];
            const int m = tid & 63, q = tid >> 6;
            {   // S1: kq[m] = h16[b,:].Wk16[m,:] + bk   (hist: fresh-addr ring, plain)
                const half_t* hp = hist + (size_t)t * HB + (size_t)b * NH + q * 128;
                const half_t* wk = Wk16 + (size_t)m * NH + q * 128;
                float s = 0.f;
#pragma unroll
                for (int j = 0; j < 128; j += 8) {
                    half8 hv = *(const half8*)(hp + j);
                    half8 wvv = *(const half8*)(wk + j);
#pragma unroll
                    for (int e2 = 0; e2 < 8; ++e2) s += (float)hv[e2] * (float)wvv[e2];
                }
                sm.e.red[tid] = s;
            }
            __syncthreads();
            if (tid < 64) {
                float s = bk[tid];
#pragma unroll
                for (int q2 = 0; q2 < 8; ++q2) s += sm.e.red[q2 * 64 + tid];
                sm.e.kqs[tid] = s;
            }
            __syncthreads();
            float s0 = 0.f, s1 = 0.f;
            {
                const half_t* mp0 = sm.e.memT + tid * 2;
#pragma unroll 8
                for (int m2 = 0; m2 < 64; ++m2) {
                    float km = sm.e.kqs[m2];
                    const half_t* mp = mp0 + m2 * MTP;
                    s0 += km * (float)mp[0];
                    s1 += km * (float)mp[1];
                }
            }
            float lmax = fmaxf(s0, s1);
            for (int o = 32; o; o >>= 1) lmax = fmaxf(lmax, __shfl_xor(lmax, o));
            if ((tid & 63) == 0) sm.e.mred[tid >> 6] = lmax;
            __syncthreads();
            float gmax = sm.e.mred[0];
#pragma unroll
            for (int q2 = 1; q2 < 8; ++q2) gmax = fmaxf(gmax, sm.e.mred[q2]);
            float e0 = __expf(s0 - gmax), e1 = __expf(s1 - gmax);
            float ls = e0 + e1;
            for (int o = 32; o; o >>= 1) ls += __shfl_xor(ls, o);
            if ((tid & 63) == 0) sm.e.sred[tid >> 6] = ls;
            sm.e.w16[tid * 2] = (half_t)e0;
            sm.e.w16[tid * 2 + 1] = (half_t)e1;
            __syncthreads();
            float wsum = 0.f;
#pragma unroll
            for (int q2 = 0; q2 < 8; ++q2) wsum += sm.e.sred[q2];
            float winv = 1.f / wsum;
            {   // S4: read[m] = (w . memT[m,:]) * winv
                const half_t* mp = sm.e.memT + m * MTP + q * 128;
                const half_t* wp = sm.e.w16 + q * 128;
                float s = 0.f;
#pragma unroll
                for (int p0 = 0; p0 < 128; p0 += 8) {
                    half8 mv = *(const half8*)(mp + p0);
                    half8 wv2 = *(const half8*)(wp + p0);
#pragma unroll
                    for (int e2 = 0; e2 < 8; ++e2) s += (float)mv[e2] * (float)wv2[e2];
                }
                sm.e.red[tid] = s;
            }
            __syncthreads();
            if (tid < 64) {
                float s = 0.f;
#pragma unroll
                for (int q2 = 0; q2 < 8; ++q2) s += sm.e.red[q2 * 64 + tid];
                sm.e.rd[tid] = s * winv;
            }
            __syncthreads();
            {   // S5: xin = x + relu(read @ Wri^T + bri); packed dword, device-scope
                const half_t* wr = Wri16 + (size_t)tid * NM;
                float s = bri[tid];
#pragma unroll
                for (int m2 = 0; m2 < 64; m2 += 8) {
                    half8 wv2 = *(const half8*)(wr + m2);
#pragma unroll
                    for (int e2 = 0; e2 < 8; ++e2) s += sm.e.rd[m2 + e2] * (float)wv2[e2];
                }
                s = fmaxf(s, 0.f) + xv;
                unsigned short u = __builtin_bit_cast(unsigned short, (half_t)s);
                unsigned short un = (unsigned short)__shfl_xor((int)u, 1);
                if ((tid & 1) == 0) {
                    unsigned pack = (unsigned)u | ((unsigned)un << 16);
                    __hip_atomic_store((unsigned*)&xin[(size_t)b * NI + tid], pack,
                                       __ATOMIC_RELAXED, __HIP_MEMORY_SCOPE_AGENT);
                }
            }
        }
        gbar(bar, ++bidx);

        // ================= phase 2: gi + gates -> h(t+1) =================
        if (bid >= NGH && bid < NGH + NGI) {
            const int gb = bid - NGH;
            const half_t* ap = xin + (size_t)(mt * 16 + row) * NI + kg * 8;  // fresh-addr ring, plain
            const half_t* bR = sm.giw + ct * 8192 + (kg * 16 + row) * 8;
            const half_t* bZ = bR + 16384;
            const half_t* bN = bR + 32768;
            f32x4 aR = {0.f,0.f,0.f,0.f}, aZ = {0.f,0.f,0.f,0.f}, aN = {0.f,0.f,0.f,0.f};
#pragma unroll
            for (int kk = 0; kk < 16; ++kk) {
                half8 a = *(const half8*)(ap + kk * 32);
                aR = __builtin_amdgcn_mfma_f32_16x16x32_f16(a, *(const half8*)(bR + kk * 512), aR, 0, 0, 0);
                aZ = __builtin_amdgcn_mfma_f32_16x16x32_f16(a, *(const half8*)(bZ + kk * 512), aZ, 0, 0, 0);
                aN = __builtin_amdgcn_mfma_f32_16x16x32_f16(a, *(const half8*)(bN + kk * 512), aN, 0, 0, 0);
            }
            int n = gb * 32 + ct * 16 + row;
            float biR = bih[n], biZ = bih[NH + n], biN = bih[2 * NH + n];
#pragma unroll
            for (int r = 0; r < 4; ++r) {
                int b2 = mt * 16 + kg * 4 + r;
                float ghr = __hip_atomic_load(&gh32[(size_t)b2 * G3 + n],
                                              __ATOMIC_RELAXED, __HIP_MEMORY_SCOPE_AGENT);
                float ghz = __hip_atomic_load(&gh32[(size_t)b2 * G3 + NH + n],
                                              __ATOMIC_RELAXED, __HIP_MEMORY_SCOPE_AGENT);
                float ghn = __hip_atomic_load(&gh32[(size_t)b2 * G3 + 2 * NH + n],
                                              __ATOMIC_RELAXED, __HIP_MEMORY_SCOPE_AGENT);
                float rg = sigm(aR[r] + biR + ghr);
                float zg = sigm(aZ[r] + biZ + ghz);
                float ng = tanhf(aN[r] + biN + rg * ghn);
                float hp = hprev[(size_t)b2 * NH + n];          // block-private
                float hn = (1.f - zg) * ng + zg * hp;
                hnext[(size_t)b2 * NH + n] = hn;                // block-private
                // hist write: packed dword, device-scope (readers cold-miss to L3)
                unsigned short u = __builtin_bit_cast(unsigned short, (half_t)hn);
                unsigned short un = (unsigned short)__shfl_xor((int)u, 1);
                if ((row & 1) == 0) {
                    unsigned pack = (unsigned)u | ((unsigned)un << 16);
                    __hip_atomic_store((unsigned*)&hist[(size_t)(t + 1) * HB + (size_t)b2 * NH + n],
                                       pack, __ATOMIC_RELAXED, __HIP_MEMORY_SCOPE_AGENT);
                }
            }
        }
        gbar(bar, ++bidx);
    }
}

// ---------------- final: out[b,t,:] = sigmoid(h_{t+1} @ Wout^T + bout) ------
__global__ __launch_bounds__(256) void out_kernel(
    const half_t* __restrict__ hist,
    const half_t* __restrict__ Wout16,
    const float* __restrict__ bout,
    float* __restrict__ out)
{
    int tid = threadIdx.x;
    int widx = tid >> 6, lane = tid & 63;
    int m0 = blockIdx.x * 64 + widx * 16;
    int row = lane & 15, kg = lane >> 4;
    const half_t* ap = hist + HB + (size_t)(m0 + row) * NH + kg * 8;
    for (int ctl = 0; ctl < 32; ++ctl) {
        int n0 = ctl * 16;
        const half_t* bp = Wout16 + (size_t)(n0 + row) * NH + kg * 8;
        f32x4 acc = {0.f, 0.f, 0.f, 0.f};
#pragma unroll
        for (int kk = 0; kk < 32; ++kk) {
            acc = __builtin_amdgcn_mfma_f32_16x16x32_f16(
                *(const half8*)(ap + kk * 32), *(const half8*)(bp + kk * 32), acc, 0, 0, 0);
        }
        int n = n0 + row;
        float bo = bout[n];
#pragma unroll
        for (int r = 0; r < 4; ++r) {
            int m = m0 + kg * 4 + r;
            int b2 = m & 63, tt = m >> 6;
            out[((size_t)b2 * NT + tt) * NI + n] = sigm(acc[r] + bo);
        }
    }
}

extern "C" void kernel_launch(void* const* d_in, const int* in_sizes, int n_in,
                              void* d_out, int out_size, void* d_ws, size_t ws_size,
                              hipStream_t stream) {
    const float* x    = (const float*)d_in[0];
    const float* mem  = (const float*)d_in[1];
    const float* Wk   = (const float*)d_in[2];
    const float* bk   = (const float*)d_in[3];
    const float* Wri  = (const float*)d_in[4];
    const float* bri  = (const float*)d_in[5];
    const float* Wih  = (const float*)d_in[6];
    const float* Whh  = (const float*)d_in[7];
    const float* bih  = (const float*)d_in[8];
    const float* bhh  = (const float*)d_in[9];
    const float* Wout = (const float*)d_in[10];
    const float* bout = (const float*)d_in[11];
    float* out = (float*)d_out;

    size_t off = 0;
    char* wsb = (char*)d_ws;
    auto carve = [&](size_t bytes) -> char* {
        char* p = wsb + off;
        off += (bytes + 255) & ~(size_t)255;
        return p;
    };
    half_t* Whh_fm  = (half_t*)carve((size_t)G3 * NH * 2);
    half_t* Wih_fm  = (half_t*)carve((size_t)G3 * NI * 2);
    half_t* Wout16  = (half_t*)carve((size_t)NI * NH * 2);
    half_t* memT16p = (half_t*)carve((size_t)NM * MTP * 2);
    half_t* Wk16    = (half_t*)carve((size_t)NM * NH * 2);
    half_t* Wri16   = (half_t*)carve((size_t)NI * NM * 2);
    half_t* hist    = (half_t*)carve((size_t)(NT + 1) * HB * 2);
    float*  h32     = (float*)carve((size_t)2 * HB * 4);
    float*  gh32    = (float*)carve((size_t)NB * G3 * 4);
    unsigned* bar   = (unsigned*)carve(256);
    half_t* xinR    = (half_t*)carve((size_t)NT * NB * NI * 2);   // 33.6 MB ring
    (void)ws_size; (void)in_sizes; (void)n_in; (void)out_size;

    prep_kernel<<<dim3(2048), dim3(256), 0, stream>>>(
        Whh, Wih, Wout, mem, Wk, Wri,
        Whh_fm, Wih_fm, Wout16, memT16p, Wk16, Wri16, hist, h32, bar);

    ntm_persist<<<dim3(GRID), dim3(512), 0, stream>>>(
        hist, h32, Whh_fm, bhh, gh32, Wih_fm, bih, x,
        memT16p, Wk16, bk, Wri16, bri, xinR, bar);

    out_kernel<<<dim3(512), dim3(256), 0, stream>>>(hist, Wout16, bout, out);
}